// Round 13
// baseline (155.436 us; speedup 1.0000x reference)
//
#include <hip/hip_runtime.h>

typedef __attribute__((ext_vector_type(8))) short short8;
typedef _Float16 half8 __attribute__((ext_vector_type(8)));
typedef __attribute__((ext_vector_type(4))) float f32x4;
typedef __attribute__((ext_vector_type(4))) unsigned int uint4v;
typedef __attribute__((ext_vector_type(2))) unsigned int uint2v;

#define B_   8
#define LX_  2048
#define LY_  2048
#define D_   256
#define NROW (B_ * LX_)   // 16384

__device__ __forceinline__ unsigned short f2bf(float f) {
  unsigned u = __builtin_bit_cast(unsigned, f);
  u += 0x7FFF + ((u >> 16) & 1);          // RNE truncate (inputs are finite)
  return (unsigned short)(u >> 16);
}
__device__ __forceinline__ float bf2f(unsigned short h) {
  unsigned u = ((unsigned)h) << 16;
  return __builtin_bit_cast(float, u);
}

// ---------------- prep: blocks 0..7 mask scan; blocks 8..39 W split ---
__global__ __launch_bounds__(256) void prep_kernel(
    const float* __restrict__ W, unsigned short* __restrict__ Whi,
    unsigned short* __restrict__ Wlo,
    const int* __restrict__ MASK, int* __restrict__ CIDX, int* __restrict__ Lc) {
  int t = threadIdx.x;
  if (blockIdx.x >= 8) {
    int base = (blockIdx.x - 8) * 2048 + t * 8;
    f32x4 f0 = *(const f32x4*)(W + base);
    f32x4 f1 = *(const f32x4*)(W + base + 4);
    float v[8] = {f0[0], f0[1], f0[2], f0[3], f1[0], f1[1], f1[2], f1[3]};
    unsigned short h[8], l[8];
    for (int j = 0; j < 8; ++j) {
      h[j] = f2bf(v[j]);
      l[j] = f2bf(v[j] - bf2f(h[j]));
    }
    uint4v vh = {(unsigned)h[0] | ((unsigned)h[1] << 16), (unsigned)h[2] | ((unsigned)h[3] << 16),
                 (unsigned)h[4] | ((unsigned)h[5] << 16), (unsigned)h[6] | ((unsigned)h[7] << 16)};
    uint4v vl = {(unsigned)l[0] | ((unsigned)l[1] << 16), (unsigned)l[2] | ((unsigned)l[3] << 16),
                 (unsigned)l[4] | ((unsigned)l[5] << 16), (unsigned)l[6] | ((unsigned)l[7] << 16)};
    *(uint4v*)(Whi + base) = vh;
    *(uint4v*)(Wlo + base) = vl;
    return;
  }
  __shared__ int s[256];
  int b = blockIdx.x;
  int f[8];
  int cnt = 0;
  for (int k = 0; k < 8; ++k) {
    f[k] = (MASK[b * 2048 + t * 8 + k] == 0) ? 1 : 0;
    cnt += f[k];
  }
  s[t] = cnt;
  __syncthreads();
  for (int off = 1; off < 256; off <<= 1) {
    int v = (t >= off) ? s[t - off] : 0;
    __syncthreads();
    s[t] += v;
    __syncthreads();
  }
  if (t == 255) Lc[b] = s[255];
  int off = s[t] - cnt;
  for (int k = 0; k < 8; ++k) {
    int j = t * 8 + k;
    if (f[k]) CIDX[b * 2048 + (off++)] = j;
  }
}

// ---------------- fused: blocks 0..511 proj ; 512..1535 gatherT -------
__global__ __launch_bounds__(256, 2) void projgather_kernel(
    const float* __restrict__ X, const float* __restrict__ Y,
    const float* __restrict__ bias,
    const unsigned short* __restrict__ Whi, const unsigned short* __restrict__ Wlo,
    const int* __restrict__ CIDX, const int* __restrict__ Lc,
    _Float16* __restrict__ XP, _Float16* __restrict__ YPc,
    _Float16* __restrict__ YTc) {
  __shared__ __align__(16) unsigned char smem[51200];
  int t = threadIdx.x;

  if (blockIdx.x >= 512) {
    // ---------------- gatherT ----------------
    _Float16 (*tile)[72] = (_Float16(*)[72])smem;
    int id = blockIdx.x - 512;
    int db = id & 3, nb = (id >> 2) & 31, b = id >> 7;
    int lc = Lc[b];
    int end = (lc + 31) & ~31;
    if (nb * 64 >= end) return;
    int nl = t >> 2, ds = t & 3;
    int j = nb * 64 + nl;
    int idx = (j < lc) ? CIDX[b * 2048 + j] : 0;
    const float* src = Y + (size_t)(b * LY_ + idx) * D_ + db * 64 + ds * 16;
    for (int i = 0; i < 4; ++i) {
      f32x4 f = *(const f32x4*)(src + i * 4);
      for (int k = 0; k < 4; ++k) tile[ds * 16 + i * 4 + k][nl] = (_Float16)f[k];
    }
    __syncthreads();
    int dl = t >> 2, nsub = t & 3;
    uint4v v0 = *(const uint4v*)&tile[dl][nsub * 16];
    uint4v v1 = *(const uint4v*)&tile[dl][nsub * 16 + 8];
    _Float16* dst = YTc + (size_t)(b * D_ + db * 64 + dl) * LY_ + nb * 64 + nsub * 16;
    *(uint4v*)(dst) = v0;
    *(uint4v*)(dst + 8) = v1;
    return;
  }

  // ---------------- proj ----------------
  unsigned short (*Ah)[40] = (unsigned short(*)[40])(smem);           // 5120
  unsigned short (*Al)[40] = (unsigned short(*)[40])(smem + 5120);    // 5120
  unsigned short (*Bh)[40] = (unsigned short(*)[40])(smem + 10240);   // 20480
  unsigned short (*Bl)[40] = (unsigned short(*)[40])(smem + 30720);   // 20480

  int lane = t & 63, wave = t >> 6;
  int q = lane >> 4, n15 = lane & 15;
  int arow = t >> 2, aseg = t & 3;
  int erow = t >> 2, ec = t & 3;

  bool isX = blockIdx.x < 256;
  int m0 = 0, b = 0, slot0 = 0, lcb = 0;
  const float* arow_ptr;
  if (isX) {
    m0 = blockIdx.x * 64;
    arow_ptr = X + (size_t)(m0 + arow) * D_;
  } else {
    int id = blockIdx.x - 256;
    b = id >> 5;
    int rb = id & 31;
    lcb = Lc[b];
    slot0 = rb * 64;
    if (slot0 >= lcb) return;          // uniform exit, no barriers crossed
    int sl = slot0 + arow;
    int grow = (sl < lcb) ? CIDX[b * 2048 + sl] : 0;
    arow_ptr = Y + (size_t)(b * 2048 + grow) * D_;
  }

  f32x4 acc[4][4];
  for (int mt = 0; mt < 4; ++mt)
    for (int nt = 0; nt < 4; ++nt) acc[mt][nt] = (f32x4){0.f, 0.f, 0.f, 0.f};

  f32x4 pa[2];
  uint4v pbh[4], pbl[4];
#define PROJ_PF(kc)                                                            \
  {                                                                            \
    for (int i = 0; i < 2; ++i)                                                \
      pa[i] = *(const f32x4*)(arow_ptr + (kc) * 32 + (aseg + i * 4) * 4);      \
    for (int p = 0; p < 4; ++p) {                                              \
      int e = p * 64 + erow;                                                   \
      pbh[p] = *(const uint4v*)(Whi + (size_t)e * D_ + (kc) * 32 + ec * 8);    \
      pbl[p] = *(const uint4v*)(Wlo + (size_t)e * D_ + (kc) * 32 + ec * 8);    \
    }                                                                          \
  }

  PROJ_PF(0);

  for (int kc = 0; kc < 8; ++kc) {
    __syncthreads();
    for (int i = 0; i < 2; ++i) {
      int seg = aseg + i * 4;
      f32x4 f = pa[i];
      unsigned short h[4], l[4];
      for (int j = 0; j < 4; ++j) {
        h[j] = f2bf(f[j]);
        l[j] = f2bf(f[j] - bf2f(h[j]));
      }
      uint2v vh = {(unsigned)h[0] | ((unsigned)h[1] << 16),
                   (unsigned)h[2] | ((unsigned)h[3] << 16)};
      uint2v vl = {(unsigned)l[0] | ((unsigned)l[1] << 16),
                   (unsigned)l[2] | ((unsigned)l[3] << 16)};
      *(uint2v*)&Ah[arow][seg * 4] = vh;
      *(uint2v*)&Al[arow][seg * 4] = vl;
    }
    for (int p = 0; p < 4; ++p) {
      int e = p * 64 + erow;
      *(uint4v*)&Bh[e][ec * 8] = pbh[p];
      *(uint4v*)&Bl[e][ec * 8] = pbl[p];
    }
    if (kc < 7) PROJ_PF(kc + 1);
    __syncthreads();

    short8 afh[4], afl[4], bfh[4], bfl[4];
    for (int mt = 0; mt < 4; ++mt) {
      afh[mt] = *(const short8*)&Ah[mt * 16 + n15][q * 8];
      afl[mt] = *(const short8*)&Al[mt * 16 + n15][q * 8];
    }
    for (int nt = 0; nt < 4; ++nt) {
      bfh[nt] = *(const short8*)&Bh[wave * 64 + nt * 16 + n15][q * 8];
      bfl[nt] = *(const short8*)&Bl[wave * 64 + nt * 16 + n15][q * 8];
    }
    for (int mt = 0; mt < 4; ++mt)
      for (int nt = 0; nt < 4; ++nt) {
        acc[mt][nt] = __builtin_amdgcn_mfma_f32_16x16x32_bf16(afh[mt], bfh[nt], acc[mt][nt], 0, 0, 0);
        acc[mt][nt] = __builtin_amdgcn_mfma_f32_16x16x32_bf16(afl[mt], bfh[nt], acc[mt][nt], 0, 0, 0);
        acc[mt][nt] = __builtin_amdgcn_mfma_f32_16x16x32_bf16(afh[mt], bfl[nt], acc[mt][nt], 0, 0, 0);
      }
  }
#undef PROJ_PF

  // ---- epilogue: bias+relu -> LDS bounce -> coalesced uint4 stores
  __syncthreads();                       // all waves done reading Bh/Bl
  _Float16 (*epi)[264] = (_Float16(*)[264])smem;   // 64 x 264 fp16 = 33792 B
  for (int nt = 0; nt < 4; ++nt) {
    int e = wave * 64 + nt * 16 + n15;
    float bv = bias[e];
    for (int mt = 0; mt < 4; ++mt)
      for (int r = 0; r < 4; ++r) {
        float v = acc[mt][nt][r] + bv;
        v = v > 0.f ? v : 0.f;
        epi[mt * 16 + q * 4 + r][e] = (_Float16)v;
      }
  }
  __syncthreads();
  int row = t >> 2, seg = t & 3;
  bool valid = isX || (slot0 + row < lcb);
  if (valid) {
    _Float16* drp = isX ? (XP + (size_t)(m0 + row) * D_)
                        : (YPc + (size_t)(b * 2048 + slot0 + row) * D_);
    for (int k = 0; k < 8; ++k) {
      uint4v v = *(const uint4v*)&epi[row][seg * 64 + k * 8];
      *(uint4v*)(drp + seg * 64 + k * 8) = v;
    }
  }
}

// ---------------- flash attention, 32-j tiles, 2-tile software pipeline
// grid 512: (b, 64 x-rows, half). 4 waves x 16 rows. NEW: double-buffered
// LDS + QK(t+1) issued BEFORE softmax(t) — the next tile's MFMAs are
// independent of the current tile's softmax VALU chain, so the two pipes
// overlap (the serial chain QK->softmax->PV was the invariant cost).
// LDS 71680 B -> 2 blocks/CU. XCD swizzle kept (r11: FETCH 26->9.2 MB).
__global__ __launch_bounds__(256, 2) void flash_kernel(
    const _Float16* __restrict__ XP, const _Float16* __restrict__ YPc,
    const _Float16* __restrict__ YTc, const int* __restrict__ Lc,
    _Float16* __restrict__ PO, float* __restrict__ Pm, float* __restrict__ Pl) {
  __shared__ __align__(16) _Float16 yp_t[2][32][264];  // 33792
  __shared__ __align__(16) _Float16 yT_t[2][256][32];  // 32768, chunk^=(rT&3)
  __shared__ __align__(16) _Float16 pbuf[4][16][40];   //  5120

  int t = threadIdx.x;
  int lane = t & 63, wave = t >> 6;
  int q = lane >> 4, n15 = lane & 15;
  int wg = (int)blockIdx.x;
  int swz = (wg & 7) * 64 + (wg >> 3);   // batch<->XCD, bijective on [0,512)
  int half = swz & 1;
  int xb = (swz >> 1) & 31;
  int b = swz >> 6;
  int row0 = xb * 64 + wave * 16;

  int lc = Lc[b];
  int T  = (lc + 31) >> 5;          // 32-j tiles
  int ts = (T * half) >> 1;
  int te = (T * (half + 1)) >> 1;

  half8 a[8];
  const _Float16* xrow = XP + (size_t)(b * LX_ + row0 + n15) * D_ + q * 8;
  for (int kk = 0; kk < 8; ++kk) a[kk] = *(const half8*)(xrow + kk * 32);

  float m_r[4];
  for (int r = 0; r < 4; ++r) m_r[r] = -1e30f;
  f32x4 lacc = {0.f, 0.f, 0.f, 0.f};
  f32x4 oacc[16];
  for (int dt = 0; dt < 16; ++dt) oacc[dt] = (f32x4){0.f, 0.f, 0.f, 0.f};

  const _Float16* ypb = YPc + (size_t)b * LY_ * D_;
  const _Float16* yTb = YTc + (size_t)b * D_ * LY_;

  uint4v pr[8];
#define PF(tt)                                                                \
  {                                                                           \
    int y0p = (tt) * 32;                                                      \
    for (int i = 0; i < 4; ++i) {                                             \
      int c = t + i * 256;                                                    \
      pr[i] = *(const uint4v*)(ypb + (size_t)(y0p + (c >> 5)) * D_ + (c & 31) * 8); \
    }                                                                         \
    for (int i = 0; i < 4; ++i) {                                             \
      int c = t + i * 256;                                                    \
      pr[4 + i] = *(const uint4v*)(yTb + (size_t)(c >> 2) * LY_ + y0p + (c & 3) * 8); \
    }                                                                         \
  }
#define STAGE(bi)                                                             \
  {                                                                           \
    for (int i = 0; i < 4; ++i) {                                             \
      int c = t + i * 256;                                                    \
      *(uint4v*)&yp_t[bi][c >> 5][(c & 31) * 8] = pr[i];                      \
    }                                                                         \
    for (int i = 0; i < 4; ++i) {                                             \
      int c = t + i * 256;                                                    \
      int rT = c >> 2, pc = (c & 3) ^ (rT & 3);                               \
      *(uint4v*)&yT_t[bi][rT][pc * 8] = pr[4 + i];                            \
    }                                                                         \
  }
#define QK(bi, S0x, S1x)                                                      \
  {                                                                           \
    S0x = (f32x4){0.f, 0.f, 0.f, 0.f};                                        \
    S1x = (f32x4){0.f, 0.f, 0.f, 0.f};                                        \
    for (int kk = 0; kk < 8; ++kk) {                                          \
      half8 b0 = *(const half8*)&yp_t[bi][n15][kk * 32 + q * 8];              \
      half8 b1 = *(const half8*)&yp_t[bi][16 + n15][kk * 32 + q * 8];         \
      S0x = __builtin_amdgcn_mfma_f32_16x16x32_f16(a[kk], b0, S0x, 0, 0, 0);  \
      S1x = __builtin_amdgcn_mfma_f32_16x16x32_f16(a[kk], b1, S1x, 0, 0, 0);  \
    }                                                                         \
  }

  f32x4 S0c = {0.f, 0.f, 0.f, 0.f}, S1c = {0.f, 0.f, 0.f, 0.f};
  f32x4 S0n = {0.f, 0.f, 0.f, 0.f}, S1n = {0.f, 0.f, 0.f, 0.f};

  if (ts < te) {
    // prologue: stage t0, QK(t0), stage t1, prefetch t2
    PF(ts);
    STAGE(ts & 1);
    if (ts + 1 < te) PF(ts + 1);
    __syncthreads();                    // buf[ts&1] staged for all waves
    QK(ts & 1, S0c, S1c);
    if (ts + 1 < te) STAGE((ts + 1) & 1);   // other buffer; no race with QK
    if (ts + 2 < te) PF(ts + 2);
    __syncthreads();                    // buf[(ts+1)&1] staged
  }

  for (int tt = ts; tt < te; ++tt) {
    int y0 = tt * 32;
    int cur = tt & 1, nxt = cur ^ 1;

    if (tt + 1 < te) QK(nxt, S0n, S1n);   // next-tile MFMAs: independent of
                                          // softmax below -> pipe overlap
    bool mk0 = (y0 + n15) >= lc;
    bool mk1 = (y0 + 16 + n15) >= lc;
    f32x4 alv;
    bool need = false;
#pragma unroll
    for (int r = 0; r < 4; ++r) {
      float s0 = mk0 ? -1e30f : S0c[r];
      float s1 = mk1 ? -1e30f : S1c[r];
      float tm = fmaxf(s0, s1);
      tm = fmaxf(tm, __shfl_xor(tm, 1));
      tm = fmaxf(tm, __shfl_xor(tm, 2));
      tm = fmaxf(tm, __shfl_xor(tm, 4));
      tm = fmaxf(tm, __shfl_xor(tm, 8));
      float mn = fmaxf(m_r[r], tm);
      float al = __expf(m_r[r] - mn);
      m_r[r] = mn;
      float p0 = __expf(s0 - mn);
      float p1 = __expf(s1 - mn);
      pbuf[wave][q * 4 + r][n15]      = (_Float16)p0;
      pbuf[wave][q * 4 + r][16 + n15] = (_Float16)p1;
      lacc[r] = lacc[r] * al + p0 + p1;
      alv[r] = al;
      need = need || (al != 1.0f);
    }
    if (__ballot(need)) {
      for (int dt = 0; dt < 16; ++dt)
        for (int r = 0; r < 4; ++r) oacc[dt][r] *= alv[r];
    }
    half8 pa = *(const half8*)&pbuf[wave][n15][q * 8];
    for (int dt = 0; dt < 16; ++dt) {
      int rT = dt * 16 + n15;
      half8 bb = *(const half8*)&yT_t[cur][rT][((q ^ (rT & 3))) * 8];
      oacc[dt] = __builtin_amdgcn_mfma_f32_16x16x32_f16(pa, bb, oacc[dt], 0, 0, 0);
    }

    __syncthreads();                    // readers of buf[cur] (PV) & buf[nxt] (QK) done
    if (tt + 2 < te) {
      STAGE(cur);                       // overwrite with tile t+2
      if (tt + 3 < te) PF(tt + 3);
    }
    __syncthreads();                    // buf[cur] staged (= next iter's nxt)
    S0c = S0n;
    S1c = S1n;
  }
#undef PF
#undef STAGE
#undef QK

  size_t prow = (size_t)(half * B_ + b) * LX_ + row0;
  _Float16* po = PO + prow * D_;
  for (int dt = 0; dt < 16; ++dt)
    for (int r = 0; r < 4; ++r)
      po[(size_t)(q * 4 + r) * D_ + dt * 16 + n15] = (_Float16)oacc[dt][r];
  // reduce per-lane partial l across the 16-lane column group
  for (int r = 0; r < 4; ++r) {
    float v = lacc[r];
    v += __shfl_xor(v, 1);
    v += __shfl_xor(v, 2);
    v += __shfl_xor(v, 4);
    v += __shfl_xor(v, 8);
    lacc[r] = v;
  }
  if (n15 == 0) {
    for (int r = 0; r < 4; ++r) {
      Pm[prow + q * 4 + r] = m_r[r];
      Pl[prow + q * 4 + r] = lacc[r];
    }
  }
}

// ---------------- merge the two tile-half partials --------------------
__global__ __launch_bounds__(256) void merge_kernel(
    const _Float16* __restrict__ PO, const float* __restrict__ Pm,
    const float* __restrict__ Pl, float* __restrict__ OUT) {
  int c = blockIdx.x * 256 + threadIdx.x;
  int row = c >> 5, seg = c & 31;
  float m0 = Pm[row], m1 = Pm[NROW + row];
  float l0 = Pl[row], l1 = Pl[NROW + row];
  float m = fmaxf(m0, m1);
  float w0 = __expf(m0 - m), w1 = __expf(m1 - m);
  float inv = 1.0f / (l0 * w0 + l1 * w1);
  const _Float16* p0 = PO + (size_t)row * D_ + seg * 8;
  const _Float16* p1 = p0 + (size_t)NROW * D_;
  half8 a = *(const half8*)p0;
  half8 bsec = *(const half8*)p1;
  float* o = OUT + (size_t)row * D_ + seg * 8;
  f32x4 o0, o1;
  for (int j = 0; j < 4; ++j) o0[j] = ((float)a[j] * w0 + (float)bsec[j] * w1) * inv;
  for (int j = 0; j < 4; ++j) o1[j] = ((float)a[4 + j] * w0 + (float)bsec[4 + j] * w1) * inv;
  *(f32x4*)o = o0;
  *(f32x4*)(o + 4) = o1;
}

extern "C" void kernel_launch(void* const* d_in, const int* in_sizes, int n_in,
                              void* d_out, int out_size, void* d_ws, size_t ws_size,
                              hipStream_t stream) {
  const float* x     = (const float*)d_in[0];  // [8,2048,256]
  const float* y     = (const float*)d_in[1];  // [8,2048,256]
  const int*   ymask = (const int*)  d_in[2];  // [8,2048]
  const float* W     = (const float*)d_in[3];  // [256,256]
  const float* bias  = (const float*)d_in[4];  // [256]
  float* out = (float*)d_out;

  // ws layout (~41 MB) — identical to the verified round-11 layout
  char* ws = (char*)d_ws;
  size_t o = 0;
  unsigned short* Whi = (unsigned short*)(ws + o); o += 131072;
  unsigned short* Wlo = (unsigned short*)(ws + o); o += 131072;
  _Float16* XP  = (_Float16*)(ws + o); o += 8388608;
  _Float16* YPc = (_Float16*)(ws + o); o += 8388608;
  _Float16* YTc = (_Float16*)(ws + o); o += 8388608;
  _Float16* PO  = (_Float16*)(ws + o); o += 16777216;   // 2 halves
  float* Pm   = (float*)(ws + o); o += 131072;
  float* Pl   = (float*)(ws + o); o += 131072;
  int*   CIDX = (int*)  (ws + o); o += 65536;
  int*   Lc   = (int*)  (ws + o);

  prep_kernel<<<40, 256, 0, stream>>>(W, Whi, Wlo, ymask, CIDX, Lc);
  projgather_kernel<<<1536, 256, 0, stream>>>(x, y, bias, Whi, Wlo, CIDX, Lc,
                                              XP, YPc, YTc);
  flash_kernel<<<512, 256, 0, stream>>>(XP, YPc, YTc, Lc, PO, Pm, Pl);
  merge_kernel<<<2048, 256, 0, stream>>>(PO, Pm, Pl, out);
}

// Round 14
// 152.259 us; speedup vs baseline: 1.0209x; 1.0209x over previous
//
#include <hip/hip_runtime.h>
#include <hip/hip_cooperative_groups.h>

typedef __attribute__((ext_vector_type(8))) short short8;
typedef _Float16 half8 __attribute__((ext_vector_type(8)));
typedef __attribute__((ext_vector_type(4))) float f32x4;
typedef __attribute__((ext_vector_type(4))) unsigned int uint4v;
typedef __attribute__((ext_vector_type(2))) unsigned int uint2v;

#define B_   8
#define LX_  2048
#define LY_  2048
#define D_   256
#define NROW (B_ * LX_)   // 16384

__device__ __forceinline__ unsigned short f2bf(float f) {
  unsigned u = __builtin_bit_cast(unsigned, f);
  u += 0x7FFF + ((u >> 16) & 1);          // RNE truncate (inputs are finite)
  return (unsigned short)(u >> 16);
}
__device__ __forceinline__ float bf2f(unsigned short h) {
  unsigned u = ((unsigned)h) << 16;
  return __builtin_bit_cast(float, u);
}

// ---------------- prep: blocks 0..7 mask scan; blocks 8..39 W split ---
__global__ __launch_bounds__(256) void prep_kernel(
    const float* __restrict__ W, unsigned short* __restrict__ Whi,
    unsigned short* __restrict__ Wlo,
    const int* __restrict__ MASK, int* __restrict__ CIDX, int* __restrict__ Lc) {
  int t = threadIdx.x;
  if (blockIdx.x >= 8) {
    int base = (blockIdx.x - 8) * 2048 + t * 8;
    f32x4 f0 = *(const f32x4*)(W + base);
    f32x4 f1 = *(const f32x4*)(W + base + 4);
    float v[8] = {f0[0], f0[1], f0[2], f0[3], f1[0], f1[1], f1[2], f1[3]};
    unsigned short h[8], l[8];
    for (int j = 0; j < 8; ++j) {
      h[j] = f2bf(v[j]);
      l[j] = f2bf(v[j] - bf2f(h[j]));
    }
    uint4v vh = {(unsigned)h[0] | ((unsigned)h[1] << 16), (unsigned)h[2] | ((unsigned)h[3] << 16),
                 (unsigned)h[4] | ((unsigned)h[5] << 16), (unsigned)h[6] | ((unsigned)h[7] << 16)};
    uint4v vl = {(unsigned)l[0] | ((unsigned)l[1] << 16), (unsigned)l[2] | ((unsigned)l[3] << 16),
                 (unsigned)l[4] | ((unsigned)l[5] << 16), (unsigned)l[6] | ((unsigned)l[7] << 16)};
    *(uint4v*)(Whi + base) = vh;
    *(uint4v*)(Wlo + base) = vl;
    return;
  }
  __shared__ int s[256];
  int b = blockIdx.x;
  int f[8];
  int cnt = 0;
  for (int k = 0; k < 8; ++k) {
    f[k] = (MASK[b * 2048 + t * 8 + k] == 0) ? 1 : 0;
    cnt += f[k];
  }
  s[t] = cnt;
  __syncthreads();
  for (int off = 1; off < 256; off <<= 1) {
    int v = (t >= off) ? s[t - off] : 0;
    __syncthreads();
    s[t] += v;
    __syncthreads();
  }
  if (t == 255) Lc[b] = s[255];
  int off = s[t] - cnt;
  for (int k = 0; k < 8; ++k) {
    int j = t * 8 + k;
    if (f[k]) CIDX[b * 2048 + (off++)] = j;
  }
}

// ---------------- fused: blocks 0..511 proj ; 512..1535 gatherT -------
__global__ __launch_bounds__(256, 2) void projgather_kernel(
    const float* __restrict__ X, const float* __restrict__ Y,
    const float* __restrict__ bias,
    const unsigned short* __restrict__ Whi, const unsigned short* __restrict__ Wlo,
    const int* __restrict__ CIDX, const int* __restrict__ Lc,
    _Float16* __restrict__ XP, _Float16* __restrict__ YPc,
    _Float16* __restrict__ YTc) {
  __shared__ __align__(16) unsigned char smem[51200];
  int t = threadIdx.x;

  if (blockIdx.x >= 512) {
    // ---------------- gatherT ----------------
    _Float16 (*tile)[72] = (_Float16(*)[72])smem;
    int id = blockIdx.x - 512;
    int db = id & 3, nb = (id >> 2) & 31, b = id >> 7;
    int lc = Lc[b];
    int end = (lc + 31) & ~31;
    if (nb * 64 >= end) return;
    int nl = t >> 2, ds = t & 3;
    int j = nb * 64 + nl;
    int idx = (j < lc) ? CIDX[b * 2048 + j] : 0;
    const float* src = Y + (size_t)(b * LY_ + idx) * D_ + db * 64 + ds * 16;
    for (int i = 0; i < 4; ++i) {
      f32x4 f = *(const f32x4*)(src + i * 4);
      for (int k = 0; k < 4; ++k) tile[ds * 16 + i * 4 + k][nl] = (_Float16)f[k];
    }
    __syncthreads();
    int dl = t >> 2, nsub = t & 3;
    uint4v v0 = *(const uint4v*)&tile[dl][nsub * 16];
    uint4v v1 = *(const uint4v*)&tile[dl][nsub * 16 + 8];
    _Float16* dst = YTc + (size_t)(b * D_ + db * 64 + dl) * LY_ + nb * 64 + nsub * 16;
    *(uint4v*)(dst) = v0;
    *(uint4v*)(dst + 8) = v1;
    return;
  }

  // ---------------- proj ----------------
  unsigned short (*Ah)[40] = (unsigned short(*)[40])(smem);           // 5120
  unsigned short (*Al)[40] = (unsigned short(*)[40])(smem + 5120);    // 5120
  unsigned short (*Bh)[40] = (unsigned short(*)[40])(smem + 10240);   // 20480
  unsigned short (*Bl)[40] = (unsigned short(*)[40])(smem + 30720);   // 20480

  int lane = t & 63, wave = t >> 6;
  int q = lane >> 4, n15 = lane & 15;
  int arow = t >> 2, aseg = t & 3;
  int erow = t >> 2, ec = t & 3;

  bool isX = blockIdx.x < 256;
  int m0 = 0, b = 0, slot0 = 0, lcb = 0;
  const float* arow_ptr;
  if (isX) {
    m0 = blockIdx.x * 64;
    arow_ptr = X + (size_t)(m0 + arow) * D_;
  } else {
    int id = blockIdx.x - 256;
    b = id >> 5;
    int rb = id & 31;
    lcb = Lc[b];
    slot0 = rb * 64;
    if (slot0 >= lcb) return;          // uniform exit, no barriers crossed
    int sl = slot0 + arow;
    int grow = (sl < lcb) ? CIDX[b * 2048 + sl] : 0;
    arow_ptr = Y + (size_t)(b * 2048 + grow) * D_;
  }

  f32x4 acc[4][4];
  for (int mt = 0; mt < 4; ++mt)
    for (int nt = 0; nt < 4; ++nt) acc[mt][nt] = (f32x4){0.f, 0.f, 0.f, 0.f};

  f32x4 pa[2];
  uint4v pbh[4], pbl[4];
#define PROJ_PF(kc)                                                            \
  {                                                                            \
    for (int i = 0; i < 2; ++i)                                                \
      pa[i] = *(const f32x4*)(arow_ptr + (kc) * 32 + (aseg + i * 4) * 4);      \
    for (int p = 0; p < 4; ++p) {                                              \
      int e = p * 64 + erow;                                                   \
      pbh[p] = *(const uint4v*)(Whi + (size_t)e * D_ + (kc) * 32 + ec * 8);    \
      pbl[p] = *(const uint4v*)(Wlo + (size_t)e * D_ + (kc) * 32 + ec * 8);    \
    }                                                                          \
  }

  PROJ_PF(0);

  for (int kc = 0; kc < 8; ++kc) {
    __syncthreads();
    for (int i = 0; i < 2; ++i) {
      int seg = aseg + i * 4;
      f32x4 f = pa[i];
      unsigned short h[4], l[4];
      for (int j = 0; j < 4; ++j) {
        h[j] = f2bf(f[j]);
        l[j] = f2bf(f[j] - bf2f(h[j]));
      }
      uint2v vh = {(unsigned)h[0] | ((unsigned)h[1] << 16),
                   (unsigned)h[2] | ((unsigned)h[3] << 16)};
      uint2v vl = {(unsigned)l[0] | ((unsigned)l[1] << 16),
                   (unsigned)l[2] | ((unsigned)l[3] << 16)};
      *(uint2v*)&Ah[arow][seg * 4] = vh;
      *(uint2v*)&Al[arow][seg * 4] = vl;
    }
    for (int p = 0; p < 4; ++p) {
      int e = p * 64 + erow;
      *(uint4v*)&Bh[e][ec * 8] = pbh[p];
      *(uint4v*)&Bl[e][ec * 8] = pbl[p];
    }
    if (kc < 7) PROJ_PF(kc + 1);
    __syncthreads();

    short8 afh[4], afl[4], bfh[4], bfl[4];
    for (int mt = 0; mt < 4; ++mt) {
      afh[mt] = *(const short8*)&Ah[mt * 16 + n15][q * 8];
      afl[mt] = *(const short8*)&Al[mt * 16 + n15][q * 8];
    }
    for (int nt = 0; nt < 4; ++nt) {
      bfh[nt] = *(const short8*)&Bh[wave * 64 + nt * 16 + n15][q * 8];
      bfl[nt] = *(const short8*)&Bl[wave * 64 + nt * 16 + n15][q * 8];
    }
    for (int mt = 0; mt < 4; ++mt)
      for (int nt = 0; nt < 4; ++nt) {
        acc[mt][nt] = __builtin_amdgcn_mfma_f32_16x16x32_bf16(afh[mt], bfh[nt], acc[mt][nt], 0, 0, 0);
        acc[mt][nt] = __builtin_amdgcn_mfma_f32_16x16x32_bf16(afl[mt], bfh[nt], acc[mt][nt], 0, 0, 0);
        acc[mt][nt] = __builtin_amdgcn_mfma_f32_16x16x32_bf16(afh[mt], bfl[nt], acc[mt][nt], 0, 0, 0);
      }
  }
#undef PROJ_PF

  // ---- epilogue: bias+relu -> LDS bounce -> coalesced uint4 stores
  __syncthreads();                       // all waves done reading Bh/Bl
  _Float16 (*epi)[264] = (_Float16(*)[264])smem;   // 64 x 264 fp16 = 33792 B
  for (int nt = 0; nt < 4; ++nt) {
    int e = wave * 64 + nt * 16 + n15;
    float bv = bias[e];
    for (int mt = 0; mt < 4; ++mt)
      for (int r = 0; r < 4; ++r) {
        float v = acc[mt][nt][r] + bv;
        v = v > 0.f ? v : 0.f;
        epi[mt * 16 + q * 4 + r][e] = (_Float16)v;
      }
  }
  __syncthreads();
  int row = t >> 2, seg = t & 3;
  bool valid = isX || (slot0 + row < lcb);
  if (valid) {
    _Float16* drp = isX ? (XP + (size_t)(m0 + row) * D_)
                        : (YPc + (size_t)(b * 2048 + slot0 + row) * D_);
    for (int k = 0; k < 8; ++k) {
      uint4v v = *(const uint4v*)&epi[row][seg * 64 + k * 8];
      *(uint4v*)(drp + seg * 64 + k * 8) = v;
    }
  }
}

// ============ flash core as a device function (r11-verified) ==========
__device__ __forceinline__ void flash_body(
    const _Float16* __restrict__ XP, const _Float16* __restrict__ YPc,
    const _Float16* __restrict__ YTc, const int* __restrict__ Lc,
    _Float16* __restrict__ PO, float* __restrict__ Pm, float* __restrict__ Pl) {
  __shared__ __align__(16) _Float16 yp_t[64][264];   // [j][d], +8 pad   33792
  __shared__ __align__(16) _Float16 yT_t[256][64];   // [d][j], chunk^row 32768
  __shared__ __align__(16) _Float16 pbuf[4][16][72]; // per-wave P        9216

  int t = threadIdx.x;
  int lane = t & 63, wave = t >> 6;
  int q = lane >> 4, n15 = lane & 15;
  // batch<->XCD swizzle: b = wg&7 (round-robin XCD id), bijective on [0,512).
  int wg = (int)blockIdx.x;
  int swz = (wg & 7) * 64 + (wg >> 3);
  int half = swz & 1;
  int xb = (swz >> 1) & 31;
  int b = swz >> 6;
  int row0 = xb * 64 + wave * 16;

  int lc = Lc[b];
  int T  = (lc + 63) >> 6;          // 64-j tiles
  int tstart = (T * half) >> 1;
  int tend   = (T * (half + 1)) >> 1;

  half8 a[8];
  const _Float16* xrow = XP + (size_t)(b * LX_ + row0 + n15) * D_ + q * 8;
  for (int kk = 0; kk < 8; ++kk) a[kk] = *(const half8*)(xrow + kk * 32);

  float m_r[4];
  for (int r = 0; r < 4; ++r) m_r[r] = -1e30f;
  f32x4 lacc = {0.f, 0.f, 0.f, 0.f};   // per-lane partial rowsum
  f32x4 oacc[16];
  for (int dt = 0; dt < 16; ++dt) oacc[dt] = (f32x4){0.f, 0.f, 0.f, 0.f};

  const _Float16* ypb = YPc + (size_t)b * LY_ * D_;
  const _Float16* yTb = YTc + (size_t)b * D_ * LY_;

  uint4v pr[16];
#define PREFETCH(tt)                                                          \
  {                                                                           \
    int y0p = (tt) * 64;                                                      \
    for (int i = 0; i < 8; ++i) {                                             \
      int c = t + i * 256;                                                    \
      pr[i] = *(const uint4v*)(ypb + (size_t)(y0p + (c >> 5)) * D_ + (c & 31) * 8); \
    }                                                                         \
    for (int i = 0; i < 8; ++i) {                                             \
      int c = t + i * 256;                                                    \
      pr[8 + i] = *(const uint4v*)(yTb + (size_t)(c >> 3) * LY_ + y0p + (c & 7) * 8); \
    }                                                                         \
  }

  if (tstart < tend) PREFETCH(tstart);

  for (int tt = tstart; tt < tend; ++tt) {
    int y0 = tt * 64;
    __syncthreads();   // A: all waves done reading previous tile
    for (int i = 0; i < 8; ++i) {
      int c = t + i * 256;
      *(uint4v*)&yp_t[c >> 5][(c & 31) * 8] = pr[i];
    }
    for (int i = 0; i < 8; ++i) {
      int c = t + i * 256;
      int rT = c >> 3, pc = (c & 7) ^ (rT & 7);       // XOR-swizzled chunk
      *(uint4v*)&yT_t[rT][pc * 8] = pr[8 + i];
    }
    if (tt + 1 < tend) PREFETCH(tt + 1);
    __syncthreads();   // B: tile staged

    f32x4 S0 = {0.f, 0.f, 0.f, 0.f}, S1 = {0.f, 0.f, 0.f, 0.f};
    f32x4 S2 = {0.f, 0.f, 0.f, 0.f}, S3 = {0.f, 0.f, 0.f, 0.f};
    for (int kk = 0; kk < 8; ++kk) {
      half8 b0 = *(const half8*)&yp_t[n15][kk * 32 + q * 8];
      half8 b1 = *(const half8*)&yp_t[16 + n15][kk * 32 + q * 8];
      half8 b2 = *(const half8*)&yp_t[32 + n15][kk * 32 + q * 8];
      half8 b3 = *(const half8*)&yp_t[48 + n15][kk * 32 + q * 8];
      S0 = __builtin_amdgcn_mfma_f32_16x16x32_f16(a[kk], b0, S0, 0, 0, 0);
      S1 = __builtin_amdgcn_mfma_f32_16x16x32_f16(a[kk], b1, S1, 0, 0, 0);
      S2 = __builtin_amdgcn_mfma_f32_16x16x32_f16(a[kk], b2, S2, 0, 0, 0);
      S3 = __builtin_amdgcn_mfma_f32_16x16x32_f16(a[kk], b3, S3, 0, 0, 0);
    }
    bool mk0 = (y0 + n15) >= lc;
    bool mk1 = (y0 + 16 + n15) >= lc;
    bool mk2 = (y0 + 32 + n15) >= lc;
    bool mk3 = (y0 + 48 + n15) >= lc;

    f32x4 alv;
    bool need = false;
#pragma unroll
    for (int r = 0; r < 4; ++r) {
      float s0 = mk0 ? -1e30f : S0[r];
      float s1 = mk1 ? -1e30f : S1[r];
      float s2 = mk2 ? -1e30f : S2[r];
      float s3 = mk3 ? -1e30f : S3[r];
      float tm = fmaxf(fmaxf(s0, s1), fmaxf(s2, s3));
      tm = fmaxf(tm, __shfl_xor(tm, 1));
      tm = fmaxf(tm, __shfl_xor(tm, 2));
      tm = fmaxf(tm, __shfl_xor(tm, 4));
      tm = fmaxf(tm, __shfl_xor(tm, 8));
      float mn = fmaxf(m_r[r], tm);
      float al = __expf(m_r[r] - mn);
      m_r[r] = mn;
      float p0 = __expf(s0 - mn);
      float p1 = __expf(s1 - mn);
      float p2 = __expf(s2 - mn);
      float p3 = __expf(s3 - mn);
      pbuf[wave][q * 4 + r][n15]      = (_Float16)p0;
      pbuf[wave][q * 4 + r][16 + n15] = (_Float16)p1;
      pbuf[wave][q * 4 + r][32 + n15] = (_Float16)p2;
      pbuf[wave][q * 4 + r][48 + n15] = (_Float16)p3;
      lacc[r] = lacc[r] * al + (p0 + p1) + (p2 + p3);
      alv[r] = al;
      need = need || (al != 1.0f);
    }
    if (__ballot(need)) {
      for (int dt = 0; dt < 16; ++dt)
        for (int r = 0; r < 4; ++r) oacc[dt][r] *= alv[r];
    }
    half8 pa0 = *(const half8*)&pbuf[wave][n15][q * 8];
    half8 pa1 = *(const half8*)&pbuf[wave][n15][32 + q * 8];
    for (int dt = 0; dt < 16; ++dt) {
      int rT = dt * 16 + n15, x = rT & 7;
      half8 bb0 = *(const half8*)&yT_t[rT][(q ^ x) * 8];
      half8 bb1 = *(const half8*)&yT_t[rT][((4 + q) ^ x) * 8];
      oacc[dt] = __builtin_amdgcn_mfma_f32_16x16x32_f16(pa0, bb0, oacc[dt], 0, 0, 0);
      oacc[dt] = __builtin_amdgcn_mfma_f32_16x16x32_f16(pa1, bb1, oacc[dt], 0, 0, 0);
    }
  }
#undef PREFETCH

  size_t prow = (size_t)(half * B_ + b) * LX_ + row0;
  _Float16* po = PO + prow * D_;
  for (int dt = 0; dt < 16; ++dt)
    for (int r = 0; r < 4; ++r)
      po[(size_t)(q * 4 + r) * D_ + dt * 16 + n15] = (_Float16)oacc[dt][r];
  // reduce per-lane partial l across the 16-lane column group
  for (int r = 0; r < 4; ++r) {
    float v = lacc[r];
    v += __shfl_xor(v, 1);
    v += __shfl_xor(v, 2);
    v += __shfl_xor(v, 4);
    v += __shfl_xor(v, 8);
    lacc[r] = v;
  }
  if (n15 == 0) {
    for (int r = 0; r < 4; ++r) {
      Pm[prow + q * 4 + r] = m_r[r];
      Pl[prow + q * 4 + r] = lacc[r];
    }
  }
}

__device__ __forceinline__ void merge_item(
    int c, const _Float16* __restrict__ PO, const float* __restrict__ Pm,
    const float* __restrict__ Pl, float* __restrict__ OUT) {
  int row = c >> 5, seg = c & 31;
  float m0 = Pm[row], m1 = Pm[NROW + row];
  float l0 = Pl[row], l1 = Pl[NROW + row];
  float m = fmaxf(m0, m1);
  float w0 = __expf(m0 - m), w1 = __expf(m1 - m);
  float inv = 1.0f / (l0 * w0 + l1 * w1);
  const _Float16* p0 = PO + (size_t)row * D_ + seg * 8;
  const _Float16* p1 = p0 + (size_t)NROW * D_;
  half8 av = *(const half8*)p0;
  half8 bv = *(const half8*)p1;
  float* o = OUT + (size_t)row * D_ + seg * 8;
  f32x4 o0, o1;
  for (int j = 0; j < 4; ++j) o0[j] = ((float)av[j] * w0 + (float)bv[j] * w1) * inv;
  for (int j = 0; j < 4; ++j) o1[j] = ((float)av[4 + j] * w0 + (float)bv[4 + j] * w1) * inv;
  *(f32x4*)o = o0;
  *(f32x4*)(o + 4) = o1;
}

// ---------------- classic pair (fallback path) ------------------------
__global__ __launch_bounds__(256, 2) void flash_kernel(
    const _Float16* __restrict__ XP, const _Float16* __restrict__ YPc,
    const _Float16* __restrict__ YTc, const int* __restrict__ Lc,
    _Float16* __restrict__ PO, float* __restrict__ Pm, float* __restrict__ Pl) {
  flash_body(XP, YPc, YTc, Lc, PO, Pm, Pl);
}

__global__ __launch_bounds__(256) void merge_kernel(
    const _Float16* __restrict__ PO, const float* __restrict__ Pm,
    const float* __restrict__ Pl, float* __restrict__ OUT) {
  merge_item(blockIdx.x * 256 + threadIdx.x, PO, Pm, Pl, OUT);
}

// ---------------- cooperative: flash + grid.sync + merge --------------
// One launch replaces flash+merge: one device-scope fence at the phase
// boundary (vs r9's per-block fences that thrashed L2 mid-loop). 512
// blocks co-resident (256 CU x 2 @ 75776 B LDS). Each block merges 1024
// of the 524288 row-segments after the sync.
__global__ __launch_bounds__(256, 2) void flashmerge_kernel(
    const _Float16* __restrict__ XP, const _Float16* __restrict__ YPc,
    const _Float16* __restrict__ YTc, const int* __restrict__ Lc,
    _Float16* __restrict__ PO, float* __restrict__ Pm, float* __restrict__ Pl,
    float* __restrict__ OUT) {
  flash_body(XP, YPc, YTc, Lc, PO, Pm, Pl);
  cooperative_groups::this_grid().sync();
  int t = threadIdx.x;
  for (int k = 0; k < 4; ++k)
    merge_item((int)blockIdx.x * 1024 + k * 256 + t, PO, Pm, Pl, OUT);
}

extern "C" void kernel_launch(void* const* d_in, const int* in_sizes, int n_in,
                              void* d_out, int out_size, void* d_ws, size_t ws_size,
                              hipStream_t stream) {
  const float* x     = (const float*)d_in[0];  // [8,2048,256]
  const float* y     = (const float*)d_in[1];  // [8,2048,256]
  const int*   ymask = (const int*)  d_in[2];  // [8,2048]
  const float* W     = (const float*)d_in[3];  // [256,256]
  const float* bias  = (const float*)d_in[4];  // [256]
  float* out = (float*)d_out;

  // ws layout (~41 MB) — identical to the verified round-11 layout
  char* ws = (char*)d_ws;
  size_t o = 0;
  unsigned short* Whi = (unsigned short*)(ws + o); o += 131072;
  unsigned short* Wlo = (unsigned short*)(ws + o); o += 131072;
  _Float16* XP  = (_Float16*)(ws + o); o += 8388608;
  _Float16* YPc = (_Float16*)(ws + o); o += 8388608;
  _Float16* YTc = (_Float16*)(ws + o); o += 8388608;
  _Float16* PO  = (_Float16*)(ws + o); o += 16777216;   // 2 halves
  float* Pm   = (float*)(ws + o); o += 131072;
  float* Pl   = (float*)(ws + o); o += 131072;
  int*   CIDX = (int*)  (ws + o); o += 65536;
  int*   Lc   = (int*)  (ws + o);

  static int coop_ok = -1;
  if (coop_ok < 0) {
    int dev = 0, v = 0;
    hipGetDevice(&dev);
    hipDeviceGetAttribute(&v, hipDeviceAttributeCooperativeLaunch, dev);
    coop_ok = v;
  }

  prep_kernel<<<40, 256, 0, stream>>>(W, Whi, Wlo, ymask, CIDX, Lc);
  projgather_kernel<<<1536, 256, 0, stream>>>(x, y, bias, Whi, Wlo, CIDX, Lc,
                                              XP, YPc, YTc);
  if (coop_ok) {
    void* args[] = {(void*)&XP, (void*)&YPc, (void*)&YTc, (void*)&Lc,
                    (void*)&PO, (void*)&Pm, (void*)&Pl, (void*)&out};
    hipError_t e = hipLaunchCooperativeKernel(
        reinterpret_cast<void*>(flashmerge_kernel), dim3(512), dim3(256),
        args, 0, stream);
    if (e == hipSuccess) return;
    coop_ok = 0;   // fall through to classic path (and stick with it)
  }
  flash_kernel<<<512, 256, 0, stream>>>(XP, YPc, YTc, Lc, PO, Pm, Pl);
  merge_kernel<<<2048, 256, 0, stream>>>(PO, Pm, Pl, out);
}

// Round 15
// 148.119 us; speedup vs baseline: 1.0494x; 1.0280x over previous
//
#include <hip/hip_runtime.h>

typedef __attribute__((ext_vector_type(8))) short short8;
typedef _Float16 half8 __attribute__((ext_vector_type(8)));
typedef __attribute__((ext_vector_type(4))) float f32x4;
typedef __attribute__((ext_vector_type(4))) unsigned int uint4v;
typedef __attribute__((ext_vector_type(2))) unsigned int uint2v;

#define B_   8
#define LX_  2048
#define LY_  2048
#define D_   256
#define NROW (B_ * LX_)   // 16384

__device__ __forceinline__ unsigned short f2bf(float f) {
  unsigned u = __builtin_bit_cast(unsigned, f);
  u += 0x7FFF + ((u >> 16) & 1);          // RNE truncate (inputs are finite)
  return (unsigned short)(u >> 16);
}
__device__ __forceinline__ float bf2f(unsigned short h) {
  unsigned u = ((unsigned)h) << 16;
  return __builtin_bit_cast(float, u);
}

// ---------------- prep: blocks 0..7 mask scan; blocks 8..39 W split ---
__global__ __launch_bounds__(256) void prep_kernel(
    const float* __restrict__ W, unsigned short* __restrict__ Whi,
    unsigned short* __restrict__ Wlo,
    const int* __restrict__ MASK, int* __restrict__ CIDX, int* __restrict__ Lc) {
  int t = threadIdx.x;
  if (blockIdx.x >= 8) {
    int base = (blockIdx.x - 8) * 2048 + t * 8;
    f32x4 f0 = *(const f32x4*)(W + base);
    f32x4 f1 = *(const f32x4*)(W + base + 4);
    float v[8] = {f0[0], f0[1], f0[2], f0[3], f1[0], f1[1], f1[2], f1[3]};
    unsigned short h[8], l[8];
    for (int j = 0; j < 8; ++j) {
      h[j] = f2bf(v[j]);
      l[j] = f2bf(v[j] - bf2f(h[j]));
    }
    uint4v vh = {(unsigned)h[0] | ((unsigned)h[1] << 16), (unsigned)h[2] | ((unsigned)h[3] << 16),
                 (unsigned)h[4] | ((unsigned)h[5] << 16), (unsigned)h[6] | ((unsigned)h[7] << 16)};
    uint4v vl = {(unsigned)l[0] | ((unsigned)l[1] << 16), (unsigned)l[2] | ((unsigned)l[3] << 16),
                 (unsigned)l[4] | ((unsigned)l[5] << 16), (unsigned)l[6] | ((unsigned)l[7] << 16)};
    *(uint4v*)(Whi + base) = vh;
    *(uint4v*)(Wlo + base) = vl;
    return;
  }
  __shared__ int s[256];
  int b = blockIdx.x;
  int f[8];
  int cnt = 0;
  for (int k = 0; k < 8; ++k) {
    f[k] = (MASK[b * 2048 + t * 8 + k] == 0) ? 1 : 0;
    cnt += f[k];
  }
  s[t] = cnt;
  __syncthreads();
  for (int off = 1; off < 256; off <<= 1) {
    int v = (t >= off) ? s[t - off] : 0;
    __syncthreads();
    s[t] += v;
    __syncthreads();
  }
  if (t == 255) Lc[b] = s[255];
  int off = s[t] - cnt;
  for (int k = 0; k < 8; ++k) {
    int j = t * 8 + k;
    if (f[k]) CIDX[b * 2048 + (off++)] = j;
  }
}

// ---------------- fused: blocks 0..511 proj ; 512..1535 gatherT -------
__global__ __launch_bounds__(256, 2) void projgather_kernel(
    const float* __restrict__ X, const float* __restrict__ Y,
    const float* __restrict__ bias,
    const unsigned short* __restrict__ Whi, const unsigned short* __restrict__ Wlo,
    const int* __restrict__ CIDX, const int* __restrict__ Lc,
    _Float16* __restrict__ XP, _Float16* __restrict__ YPc,
    _Float16* __restrict__ YTc) {
  __shared__ __align__(16) unsigned char smem[51200];
  int t = threadIdx.x;

  if (blockIdx.x >= 512) {
    // ---------------- gatherT ----------------
    _Float16 (*tile)[72] = (_Float16(*)[72])smem;
    int id = blockIdx.x - 512;
    int db = id & 3, nb = (id >> 2) & 31, b = id >> 7;
    int lc = Lc[b];
    int end = (lc + 31) & ~31;
    if (nb * 64 >= end) return;
    int nl = t >> 2, ds = t & 3;
    int j = nb * 64 + nl;
    int idx = (j < lc) ? CIDX[b * 2048 + j] : 0;
    const float* src = Y + (size_t)(b * LY_ + idx) * D_ + db * 64 + ds * 16;
    for (int i = 0; i < 4; ++i) {
      f32x4 f = *(const f32x4*)(src + i * 4);
      for (int k = 0; k < 4; ++k) tile[ds * 16 + i * 4 + k][nl] = (_Float16)f[k];
    }
    __syncthreads();
    int dl = t >> 2, nsub = t & 3;
    uint4v v0 = *(const uint4v*)&tile[dl][nsub * 16];
    uint4v v1 = *(const uint4v*)&tile[dl][nsub * 16 + 8];
    _Float16* dst = YTc + (size_t)(b * D_ + db * 64 + dl) * LY_ + nb * 64 + nsub * 16;
    *(uint4v*)(dst) = v0;
    *(uint4v*)(dst + 8) = v1;
    return;
  }

  // ---------------- proj ----------------
  unsigned short (*Ah)[40] = (unsigned short(*)[40])(smem);           // 5120
  unsigned short (*Al)[40] = (unsigned short(*)[40])(smem + 5120);    // 5120
  unsigned short (*Bh)[40] = (unsigned short(*)[40])(smem + 10240);   // 20480
  unsigned short (*Bl)[40] = (unsigned short(*)[40])(smem + 30720);   // 20480

  int lane = t & 63, wave = t >> 6;
  int q = lane >> 4, n15 = lane & 15;
  int arow = t >> 2, aseg = t & 3;
  int erow = t >> 2, ec = t & 3;

  bool isX = blockIdx.x < 256;
  int m0 = 0, b = 0, slot0 = 0, lcb = 0;
  const float* arow_ptr;
  if (isX) {
    m0 = blockIdx.x * 64;
    arow_ptr = X + (size_t)(m0 + arow) * D_;
  } else {
    int id = blockIdx.x - 256;
    b = id >> 5;
    int rb = id & 31;
    lcb = Lc[b];
    slot0 = rb * 64;
    if (slot0 >= lcb) return;          // uniform exit, no barriers crossed
    int sl = slot0 + arow;
    int grow = (sl < lcb) ? CIDX[b * 2048 + sl] : 0;
    arow_ptr = Y + (size_t)(b * 2048 + grow) * D_;
  }

  f32x4 acc[4][4];
  for (int mt = 0; mt < 4; ++mt)
    for (int nt = 0; nt < 4; ++nt) acc[mt][nt] = (f32x4){0.f, 0.f, 0.f, 0.f};

  f32x4 pa[2];
  uint4v pbh[4], pbl[4];
#define PROJ_PF(kc)                                                            \
  {                                                                            \
    for (int i = 0; i < 2; ++i)                                                \
      pa[i] = *(const f32x4*)(arow_ptr + (kc) * 32 + (aseg + i * 4) * 4);      \
    for (int p = 0; p < 4; ++p) {                                              \
      int e = p * 64 + erow;                                                   \
      pbh[p] = *(const uint4v*)(Whi + (size_t)e * D_ + (kc) * 32 + ec * 8);    \
      pbl[p] = *(const uint4v*)(Wlo + (size_t)e * D_ + (kc) * 32 + ec * 8);    \
    }                                                                          \
  }

  PROJ_PF(0);

  for (int kc = 0; kc < 8; ++kc) {
    __syncthreads();
    for (int i = 0; i < 2; ++i) {
      int seg = aseg + i * 4;
      f32x4 f = pa[i];
      unsigned short h[4], l[4];
      for (int j = 0; j < 4; ++j) {
        h[j] = f2bf(f[j]);
        l[j] = f2bf(f[j] - bf2f(h[j]));
      }
      uint2v vh = {(unsigned)h[0] | ((unsigned)h[1] << 16),
                   (unsigned)h[2] | ((unsigned)h[3] << 16)};
      uint2v vl = {(unsigned)l[0] | ((unsigned)l[1] << 16),
                   (unsigned)l[2] | ((unsigned)l[3] << 16)};
      *(uint2v*)&Ah[arow][seg * 4] = vh;
      *(uint2v*)&Al[arow][seg * 4] = vl;
    }
    for (int p = 0; p < 4; ++p) {
      int e = p * 64 + erow;
      *(uint4v*)&Bh[e][ec * 8] = pbh[p];
      *(uint4v*)&Bl[e][ec * 8] = pbl[p];
    }
    if (kc < 7) PROJ_PF(kc + 1);
    __syncthreads();

    short8 afh[4], afl[4], bfh[4], bfl[4];
    for (int mt = 0; mt < 4; ++mt) {
      afh[mt] = *(const short8*)&Ah[mt * 16 + n15][q * 8];
      afl[mt] = *(const short8*)&Al[mt * 16 + n15][q * 8];
    }
    for (int nt = 0; nt < 4; ++nt) {
      bfh[nt] = *(const short8*)&Bh[wave * 64 + nt * 16 + n15][q * 8];
      bfl[nt] = *(const short8*)&Bl[wave * 64 + nt * 16 + n15][q * 8];
    }
    for (int mt = 0; mt < 4; ++mt)
      for (int nt = 0; nt < 4; ++nt) {
        acc[mt][nt] = __builtin_amdgcn_mfma_f32_16x16x32_bf16(afh[mt], bfh[nt], acc[mt][nt], 0, 0, 0);
        acc[mt][nt] = __builtin_amdgcn_mfma_f32_16x16x32_bf16(afl[mt], bfh[nt], acc[mt][nt], 0, 0, 0);
        acc[mt][nt] = __builtin_amdgcn_mfma_f32_16x16x32_bf16(afh[mt], bfl[nt], acc[mt][nt], 0, 0, 0);
      }
  }
#undef PROJ_PF

  // ---- epilogue: bias+relu -> LDS bounce -> coalesced uint4 stores
  __syncthreads();                       // all waves done reading Bh/Bl
  _Float16 (*epi)[264] = (_Float16(*)[264])smem;   // 64 x 264 fp16 = 33792 B
  for (int nt = 0; nt < 4; ++nt) {
    int e = wave * 64 + nt * 16 + n15;
    float bv = bias[e];
    for (int mt = 0; mt < 4; ++mt)
      for (int r = 0; r < 4; ++r) {
        float v = acc[mt][nt][r] + bv;
        v = v > 0.f ? v : 0.f;
        epi[mt * 16 + q * 4 + r][e] = (_Float16)v;
      }
  }
  __syncthreads();
  int row = t >> 2, seg = t & 3;
  bool valid = isX || (slot0 + row < lcb);
  if (valid) {
    _Float16* drp = isX ? (XP + (size_t)(m0 + row) * D_)
                        : (YPc + (size_t)(b * 2048 + slot0 + row) * D_);
    for (int k = 0; k < 8; ++k) {
      uint4v v = *(const uint4v*)&epi[row][seg * 64 + k * 8];
      *(uint4v*)(drp + seg * 64 + k * 8) = v;
    }
  }
}

// ---------------- flash + in-block merge, 64-j tiles ------------------
// grid 256, 512 threads (8 waves = two 4-wave groups). Both groups cover
// the SAME 64 x-rows; group g does tile range [T*g/2, T*(g+1)/2). The
// r8-verified core runs per group on private LDS buffers. Groups execute
// a UNIFORM iteration count (nit = ceil(T/2)); invalid trailing iters
// still hit both barriers (no divergent-barrier hazard). At the end,
// group 1 parks O(fp16)+m+l in the freed staging LDS; group 0 combines
// (its half stays fp32 in regs) and writes OUT directly. merge_kernel,
// PO/Pm/Pl, and one launch boundary are deleted. LDS 151552 B ->
// 1 block/CU = 8 waves/CU (same as 2x4 before). XCD swizzle kept.
__global__ __launch_bounds__(512, 2) void flashout_kernel(
    const _Float16* __restrict__ XP, const _Float16* __restrict__ YPc,
    const _Float16* __restrict__ YTc, const int* __restrict__ Lc,
    float* __restrict__ OUT) {
  __shared__ __align__(16) _Float16 yp_t[2][64][264];   // 67584
  __shared__ __align__(16) _Float16 yT_t[2][256][64];   // 65536, chunk^row
  __shared__ __align__(16) _Float16 pbuf[8][16][72];    // 18432

  int t = threadIdx.x;                 // 0..511
  int lane = t & 63, wave = t >> 6;    // wave 0..7
  int g = wave >> 2;                   // tile-half group 0/1
  int wv = wave & 3;                   // wave-in-group
  int tl = t & 255;                    // thread-in-group
  int q = lane >> 4, n15 = lane & 15;
  int wg = (int)blockIdx.x;            // 0..255
  int swz = (wg & 7) * 32 + (wg >> 3); // batch<->XCD, bijective on [0,256)
  int xb = swz & 31;
  int b = swz >> 5;
  int row0 = xb * 64 + wv * 16;

  int lc = Lc[b];
  int T  = (lc + 63) >> 6;             // 64-j tiles
  int tstart = (T * g) >> 1;
  int tend   = (T * (g + 1)) >> 1;
  int nit    = T - (T >> 1);           // ceil(T/2) >= both group counts

  half8 a[8];
  const _Float16* xrow = XP + (size_t)(b * LX_ + row0 + n15) * D_ + q * 8;
  for (int kk = 0; kk < 8; ++kk) a[kk] = *(const half8*)(xrow + kk * 32);

  float m_r[4];
  for (int r = 0; r < 4; ++r) m_r[r] = -1e30f;
  f32x4 lacc = {0.f, 0.f, 0.f, 0.f};
  f32x4 oacc[16];
  for (int dt = 0; dt < 16; ++dt) oacc[dt] = (f32x4){0.f, 0.f, 0.f, 0.f};

  const _Float16* ypb = YPc + (size_t)b * LY_ * D_;
  const _Float16* yTb = YTc + (size_t)b * D_ * LY_;

  uint4v pr[16];
#define PREFETCH(tt)                                                          \
  {                                                                           \
    int y0p = (tt) * 64;                                                      \
    for (int i = 0; i < 8; ++i) {                                             \
      int c = tl + i * 256;                                                   \
      pr[i] = *(const uint4v*)(ypb + (size_t)(y0p + (c >> 5)) * D_ + (c & 31) * 8); \
    }                                                                         \
    for (int i = 0; i < 8; ++i) {                                             \
      int c = tl + i * 256;                                                   \
      pr[8 + i] = *(const uint4v*)(yTb + (size_t)(c >> 3) * LY_ + y0p + (c & 7) * 8); \
    }                                                                         \
  }

  if (tstart < tend) PREFETCH(tstart);

  for (int it = 0; it < nit; ++it) {
    int tt = tstart + it;
    bool val = tt < tend;
    int y0 = tt * 64;
    __syncthreads();   // A: all waves done reading previous tile
    if (val) {
      for (int i = 0; i < 8; ++i) {
        int c = tl + i * 256;
        *(uint4v*)&yp_t[g][c >> 5][(c & 31) * 8] = pr[i];
      }
      for (int i = 0; i < 8; ++i) {
        int c = tl + i * 256;
        int rT = c >> 3, pc = (c & 7) ^ (rT & 7);     // XOR-swizzled chunk
        *(uint4v*)&yT_t[g][rT][pc * 8] = pr[8 + i];
      }
      if (tt + 1 < tend) PREFETCH(tt + 1);
    }
    __syncthreads();   // B: tile staged
    if (!val) continue;   // barriers done; compute section has none

    f32x4 S0 = {0.f, 0.f, 0.f, 0.f}, S1 = {0.f, 0.f, 0.f, 0.f};
    f32x4 S2 = {0.f, 0.f, 0.f, 0.f}, S3 = {0.f, 0.f, 0.f, 0.f};
    for (int kk = 0; kk < 8; ++kk) {
      half8 b0 = *(const half8*)&yp_t[g][n15][kk * 32 + q * 8];
      half8 b1 = *(const half8*)&yp_t[g][16 + n15][kk * 32 + q * 8];
      half8 b2 = *(const half8*)&yp_t[g][32 + n15][kk * 32 + q * 8];
      half8 b3 = *(const half8*)&yp_t[g][48 + n15][kk * 32 + q * 8];
      S0 = __builtin_amdgcn_mfma_f32_16x16x32_f16(a[kk], b0, S0, 0, 0, 0);
      S1 = __builtin_amdgcn_mfma_f32_16x16x32_f16(a[kk], b1, S1, 0, 0, 0);
      S2 = __builtin_amdgcn_mfma_f32_16x16x32_f16(a[kk], b2, S2, 0, 0, 0);
      S3 = __builtin_amdgcn_mfma_f32_16x16x32_f16(a[kk], b3, S3, 0, 0, 0);
    }
    bool mk0 = (y0 + n15) >= lc;
    bool mk1 = (y0 + 16 + n15) >= lc;
    bool mk2 = (y0 + 32 + n15) >= lc;
    bool mk3 = (y0 + 48 + n15) >= lc;

    f32x4 alv;
    bool need = false;
#pragma unroll
    for (int r = 0; r < 4; ++r) {
      float s0 = mk0 ? -1e30f : S0[r];
      float s1 = mk1 ? -1e30f : S1[r];
      float s2 = mk2 ? -1e30f : S2[r];
      float s3 = mk3 ? -1e30f : S3[r];
      float tm = fmaxf(fmaxf(s0, s1), fmaxf(s2, s3));
      tm = fmaxf(tm, __shfl_xor(tm, 1));
      tm = fmaxf(tm, __shfl_xor(tm, 2));
      tm = fmaxf(tm, __shfl_xor(tm, 4));
      tm = fmaxf(tm, __shfl_xor(tm, 8));
      float mn = fmaxf(m_r[r], tm);
      float al = __expf(m_r[r] - mn);
      m_r[r] = mn;
      float p0 = __expf(s0 - mn);
      float p1 = __expf(s1 - mn);
      float p2 = __expf(s2 - mn);
      float p3 = __expf(s3 - mn);
      pbuf[wave][q * 4 + r][n15]      = (_Float16)p0;
      pbuf[wave][q * 4 + r][16 + n15] = (_Float16)p1;
      pbuf[wave][q * 4 + r][32 + n15] = (_Float16)p2;
      pbuf[wave][q * 4 + r][48 + n15] = (_Float16)p3;
      lacc[r] = lacc[r] * al + (p0 + p1) + (p2 + p3);
      alv[r] = al;
      need = need || (al != 1.0f);
    }
    if (__ballot(need)) {
      for (int dt = 0; dt < 16; ++dt)
        for (int r = 0; r < 4; ++r) oacc[dt][r] *= alv[r];
    }
    half8 pa0 = *(const half8*)&pbuf[wave][n15][q * 8];
    half8 pa1 = *(const half8*)&pbuf[wave][n15][32 + q * 8];
    for (int dt = 0; dt < 16; ++dt) {
      int rT = dt * 16 + n15, x = rT & 7;
      half8 bb0 = *(const half8*)&yT_t[g][rT][(q ^ x) * 8];
      half8 bb1 = *(const half8*)&yT_t[g][rT][((4 + q) ^ x) * 8];
      oacc[dt] = __builtin_amdgcn_mfma_f32_16x16x32_f16(pa0, bb0, oacc[dt], 0, 0, 0);
      oacc[dt] = __builtin_amdgcn_mfma_f32_16x16x32_f16(pa1, bb1, oacc[dt], 0, 0, 0);
    }
  }
#undef PREFETCH

  // reduce per-lane partial l across the 16-lane column group
  for (int r = 0; r < 4; ++r) {
    float v = lacc[r];
    v += __shfl_xor(v, 1);
    v += __shfl_xor(v, 2);
    v += __shfl_xor(v, 4);
    v += __shfl_xor(v, 8);
    lacc[r] = v;
  }

  // ---- in-block merge of the two tile-halves --------------------------
  __syncthreads();   // all staging reads done; LDS reusable
  _Float16 (*Obuf)[256] = (_Float16(*)[256])&yp_t[0][0][0];  // 32768 B
  float (*ml)[2] = (float(*)[2])&yT_t[0][0][0];              //   512 B
  if (g == 1) {
    for (int dt = 0; dt < 16; ++dt)
      for (int r = 0; r < 4; ++r)
        Obuf[wv * 16 + q * 4 + r][dt * 16 + n15] = (_Float16)oacc[dt][r];
    if (n15 == 0)
      for (int r = 0; r < 4; ++r) {
        ml[wv * 16 + q * 4 + r][0] = m_r[r];
        ml[wv * 16 + q * 4 + r][1] = lacc[r];
      }
  }
  __syncthreads();
  if (g == 0) {
    for (int r = 0; r < 4; ++r) {
      int rl = wv * 16 + q * 4 + r;
      float m1 = ml[rl][0], l1 = ml[rl][1];
      float m0 = m_r[r], l0 = lacc[r];
      float mm = fmaxf(m0, m1);
      float w0 = __expf(m0 - mm), w1 = __expf(m1 - mm);
      float inv = 1.0f / (l0 * w0 + l1 * w1);
      float* orow = OUT + (size_t)(b * LX_ + xb * 64 + rl) * D_;
      for (int dt = 0; dt < 16; ++dt) {
        float o1 = (float)Obuf[rl][dt * 16 + n15];
        orow[dt * 16 + n15] = (oacc[dt][r] * w0 + o1 * w1) * inv;
      }
    }
  }
}

extern "C" void kernel_launch(void* const* d_in, const int* in_sizes, int n_in,
                              void* d_out, int out_size, void* d_ws, size_t ws_size,
                              hipStream_t stream) {
  const float* x     = (const float*)d_in[0];  // [8,2048,256]
  const float* y     = (const float*)d_in[1];  // [8,2048,256]
  const int*   ymask = (const int*)  d_in[2];  // [8,2048]
  const float* W     = (const float*)d_in[3];  // [256,256]
  const float* bias  = (const float*)d_in[4];  // [256]
  float* out = (float*)d_out;

  // ws layout (~25 MB): PO/Pm/Pl no longer needed
  char* ws = (char*)d_ws;
  size_t o = 0;
  unsigned short* Whi = (unsigned short*)(ws + o); o += 131072;
  unsigned short* Wlo = (unsigned short*)(ws + o); o += 131072;
  _Float16* XP  = (_Float16*)(ws + o); o += 8388608;
  _Float16* YPc = (_Float16*)(ws + o); o += 8388608;
  _Float16* YTc = (_Float16*)(ws + o); o += 8388608;
  int*   CIDX = (int*)  (ws + o); o += 65536;
  int*   Lc   = (int*)  (ws + o);

  prep_kernel<<<40, 256, 0, stream>>>(W, Whi, Wlo, ymask, CIDX, Lc);
  projgather_kernel<<<1536, 256, 0, stream>>>(x, y, bias, Whi, Wlo, CIDX, Lc,
                                              XP, YPc, YTc);
  flashout_kernel<<<256, 512, 0, stream>>>(XP, YPc, YTc, Lc, out);
}

// Round 16
// 147.163 us; speedup vs baseline: 1.0562x; 1.0065x over previous
//
#include <hip/hip_runtime.h>

typedef __attribute__((ext_vector_type(8))) short short8;
typedef _Float16 half8 __attribute__((ext_vector_type(8)));
typedef __attribute__((ext_vector_type(4))) float f32x4;
typedef __attribute__((ext_vector_type(4))) unsigned int uint4v;
typedef __attribute__((ext_vector_type(2))) unsigned int uint2v;

#define B_   8
#define LX_  2048
#define LY_  2048
#define D_   256
#define NROW (B_ * LX_)   // 16384

__device__ __forceinline__ unsigned short f2bf(float f) {
  unsigned u = __builtin_bit_cast(unsigned, f);
  u += 0x7FFF + ((u >> 16) & 1);          // RNE truncate (inputs are finite)
  return (unsigned short)(u >> 16);
}
__device__ __forceinline__ float bf2f(unsigned short h) {
  unsigned u = ((unsigned)h) << 16;
  return __builtin_bit_cast(float, u);
}

// ---------------- prep: blocks 0..7 mask scan; blocks 8..39 W split ---
__global__ __launch_bounds__(256) void prep_kernel(
    const float* __restrict__ W, unsigned short* __restrict__ Whi,
    unsigned short* __restrict__ Wlo,
    const int* __restrict__ MASK, int* __restrict__ CIDX, int* __restrict__ Lc) {
  int t = threadIdx.x;
  if (blockIdx.x >= 8) {
    int base = (blockIdx.x - 8) * 2048 + t * 8;
    f32x4 f0 = *(const f32x4*)(W + base);
    f32x4 f1 = *(const f32x4*)(W + base + 4);
    float v[8] = {f0[0], f0[1], f0[2], f0[3], f1[0], f1[1], f1[2], f1[3]};
    unsigned short h[8], l[8];
    for (int j = 0; j < 8; ++j) {
      h[j] = f2bf(v[j]);
      l[j] = f2bf(v[j] - bf2f(h[j]));
    }
    uint4v vh = {(unsigned)h[0] | ((unsigned)h[1] << 16), (unsigned)h[2] | ((unsigned)h[3] << 16),
                 (unsigned)h[4] | ((unsigned)h[5] << 16), (unsigned)h[6] | ((unsigned)h[7] << 16)};
    uint4v vl = {(unsigned)l[0] | ((unsigned)l[1] << 16), (unsigned)l[2] | ((unsigned)l[3] << 16),
                 (unsigned)l[4] | ((unsigned)l[5] << 16), (unsigned)l[6] | ((unsigned)l[7] << 16)};
    *(uint4v*)(Whi + base) = vh;
    *(uint4v*)(Wlo + base) = vl;
    return;
  }
  __shared__ int s[256];
  int b = blockIdx.x;
  int f[8];
  int cnt = 0;
  for (int k = 0; k < 8; ++k) {
    f[k] = (MASK[b * 2048 + t * 8 + k] == 0) ? 1 : 0;
    cnt += f[k];
  }
  s[t] = cnt;
  __syncthreads();
  for (int off = 1; off < 256; off <<= 1) {
    int v = (t >= off) ? s[t - off] : 0;
    __syncthreads();
    s[t] += v;
    __syncthreads();
  }
  if (t == 255) Lc[b] = s[255];
  int off = s[t] - cnt;
  for (int k = 0; k < 8; ++k) {
    int j = t * 8 + k;
    if (f[k]) CIDX[b * 2048 + (off++)] = j;
  }
}

// ---------------- fused: blocks 0..511 proj ; 512..1535 gatherT -------
// r16 single delta: __launch_bounds__(256,3) — 3 blocks/CU (LDS 3x51200
// = 153600 <= 163840; live set ~140 <= 170-reg budget). 1536 blocks run
// in 2 occupancy rounds instead of 3. Spill tripwire: projgather would
// surface in top-5 with inflated WRITE_SIZE.
__global__ __launch_bounds__(256, 3) void projgather_kernel(
    const float* __restrict__ X, const float* __restrict__ Y,
    const float* __restrict__ bias,
    const unsigned short* __restrict__ Whi, const unsigned short* __restrict__ Wlo,
    const int* __restrict__ CIDX, const int* __restrict__ Lc,
    _Float16* __restrict__ XP, _Float16* __restrict__ YPc,
    _Float16* __restrict__ YTc) {
  __shared__ __align__(16) unsigned char smem[51200];
  int t = threadIdx.x;

  if (blockIdx.x >= 512) {
    // ---------------- gatherT ----------------
    _Float16 (*tile)[72] = (_Float16(*)[72])smem;
    int id = blockIdx.x - 512;
    int db = id & 3, nb = (id >> 2) & 31, b = id >> 7;
    int lc = Lc[b];
    int end = (lc + 31) & ~31;
    if (nb * 64 >= end) return;
    int nl = t >> 2, ds = t & 3;
    int j = nb * 64 + nl;
    int idx = (j < lc) ? CIDX[b * 2048 + j] : 0;
    const float* src = Y + (size_t)(b * LY_ + idx) * D_ + db * 64 + ds * 16;
    for (int i = 0; i < 4; ++i) {
      f32x4 f = *(const f32x4*)(src + i * 4);
      for (int k = 0; k < 4; ++k) tile[ds * 16 + i * 4 + k][nl] = (_Float16)f[k];
    }
    __syncthreads();
    int dl = t >> 2, nsub = t & 3;
    uint4v v0 = *(const uint4v*)&tile[dl][nsub * 16];
    uint4v v1 = *(const uint4v*)&tile[dl][nsub * 16 + 8];
    _Float16* dst = YTc + (size_t)(b * D_ + db * 64 + dl) * LY_ + nb * 64 + nsub * 16;
    *(uint4v*)(dst) = v0;
    *(uint4v*)(dst + 8) = v1;
    return;
  }

  // ---------------- proj ----------------
  unsigned short (*Ah)[40] = (unsigned short(*)[40])(smem);           // 5120
  unsigned short (*Al)[40] = (unsigned short(*)[40])(smem + 5120);    // 5120
  unsigned short (*Bh)[40] = (unsigned short(*)[40])(smem + 10240);   // 20480
  unsigned short (*Bl)[40] = (unsigned short(*)[40])(smem + 30720);   // 20480

  int lane = t & 63, wave = t >> 6;
  int q = lane >> 4, n15 = lane & 15;
  int arow = t >> 2, aseg = t & 3;
  int erow = t >> 2, ec = t & 3;

  bool isX = blockIdx.x < 256;
  int m0 = 0, b = 0, slot0 = 0, lcb = 0;
  const float* arow_ptr;
  if (isX) {
    m0 = blockIdx.x * 64;
    arow_ptr = X + (size_t)(m0 + arow) * D_;
  } else {
    int id = blockIdx.x - 256;
    b = id >> 5;
    int rb = id & 31;
    lcb = Lc[b];
    slot0 = rb * 64;
    if (slot0 >= lcb) return;          // uniform exit, no barriers crossed
    int sl = slot0 + arow;
    int grow = (sl < lcb) ? CIDX[b * 2048 + sl] : 0;
    arow_ptr = Y + (size_t)(b * 2048 + grow) * D_;
  }

  f32x4 acc[4][4];
  for (int mt = 0; mt < 4; ++mt)
    for (int nt = 0; nt < 4; ++nt) acc[mt][nt] = (f32x4){0.f, 0.f, 0.f, 0.f};

  f32x4 pa[2];
  uint4v pbh[4], pbl[4];
#define PROJ_PF(kc)                                                            \
  {                                                                            \
    for (int i = 0; i < 2; ++i)                                                \
      pa[i] = *(const f32x4*)(arow_ptr + (kc) * 32 + (aseg + i * 4) * 4);      \
    for (int p = 0; p < 4; ++p) {                                              \
      int e = p * 64 + erow;                                                   \
      pbh[p] = *(const uint4v*)(Whi + (size_t)e * D_ + (kc) * 32 + ec * 8);    \
      pbl[p] = *(const uint4v*)(Wlo + (size_t)e * D_ + (kc) * 32 + ec * 8);    \
    }                                                                          \
  }

  PROJ_PF(0);

  for (int kc = 0; kc < 8; ++kc) {
    __syncthreads();
    for (int i = 0; i < 2; ++i) {
      int seg = aseg + i * 4;
      f32x4 f = pa[i];
      unsigned short h[4], l[4];
      for (int j = 0; j < 4; ++j) {
        h[j] = f2bf(f[j]);
        l[j] = f2bf(f[j] - bf2f(h[j]));
      }
      uint2v vh = {(unsigned)h[0] | ((unsigned)h[1] << 16),
                   (unsigned)h[2] | ((unsigned)h[3] << 16)};
      uint2v vl = {(unsigned)l[0] | ((unsigned)l[1] << 16),
                   (unsigned)l[2] | ((unsigned)l[3] << 16)};
      *(uint2v*)&Ah[arow][seg * 4] = vh;
      *(uint2v*)&Al[arow][seg * 4] = vl;
    }
    for (int p = 0; p < 4; ++p) {
      int e = p * 64 + erow;
      *(uint4v*)&Bh[e][ec * 8] = pbh[p];
      *(uint4v*)&Bl[e][ec * 8] = pbl[p];
    }
    if (kc < 7) PROJ_PF(kc + 1);
    __syncthreads();

    short8 afh[4], afl[4], bfh[4], bfl[4];
    for (int mt = 0; mt < 4; ++mt) {
      afh[mt] = *(const short8*)&Ah[mt * 16 + n15][q * 8];
      afl[mt] = *(const short8*)&Al[mt * 16 + n15][q * 8];
    }
    for (int nt = 0; nt < 4; ++nt) {
      bfh[nt] = *(const short8*)&Bh[wave * 64 + nt * 16 + n15][q * 8];
      bfl[nt] = *(const short8*)&Bl[wave * 64 + nt * 16 + n15][q * 8];
    }
    for (int mt = 0; mt < 4; ++mt)
      for (int nt = 0; nt < 4; ++nt) {
        acc[mt][nt] = __builtin_amdgcn_mfma_f32_16x16x32_bf16(afh[mt], bfh[nt], acc[mt][nt], 0, 0, 0);
        acc[mt][nt] = __builtin_amdgcn_mfma_f32_16x16x32_bf16(afl[mt], bfh[nt], acc[mt][nt], 0, 0, 0);
        acc[mt][nt] = __builtin_amdgcn_mfma_f32_16x16x32_bf16(afh[mt], bfl[nt], acc[mt][nt], 0, 0, 0);
      }
  }
#undef PROJ_PF

  // ---- epilogue: bias+relu -> LDS bounce -> coalesced uint4 stores
  __syncthreads();                       // all waves done reading Bh/Bl
  _Float16 (*epi)[264] = (_Float16(*)[264])smem;   // 64 x 264 fp16 = 33792 B
  for (int nt = 0; nt < 4; ++nt) {
    int e = wave * 64 + nt * 16 + n15;
    float bv = bias[e];
    for (int mt = 0; mt < 4; ++mt)
      for (int r = 0; r < 4; ++r) {
        float v = acc[mt][nt][r] + bv;
        v = v > 0.f ? v : 0.f;
        epi[mt * 16 + q * 4 + r][e] = (_Float16)v;
      }
  }
  __syncthreads();
  int row = t >> 2, seg = t & 3;
  bool valid = isX || (slot0 + row < lcb);
  if (valid) {
    _Float16* drp = isX ? (XP + (size_t)(m0 + row) * D_)
                        : (YPc + (size_t)(b * 2048 + slot0 + row) * D_);
    for (int k = 0; k < 8; ++k) {
      uint4v v = *(const uint4v*)&epi[row][seg * 64 + k * 8];
      *(uint4v*)(drp + seg * 64 + k * 8) = v;
    }
  }
}

// ---------------- flash + in-block merge, 64-j tiles ------------------
// grid 256, 512 threads (8 waves = two 4-wave groups). Both groups cover
// the SAME 64 x-rows; group g does tile range [T*g/2, T*(g+1)/2). The
// r8-verified core runs per group on private LDS buffers. Groups execute
// a UNIFORM iteration count (nit = ceil(T/2)); invalid trailing iters
// still hit both barriers (no divergent-barrier hazard). At the end,
// group 1 parks O(fp16)+m+l in the freed staging LDS; group 0 combines
// (its half stays fp32 in regs) and writes OUT directly. LDS 151552 B ->
// 1 block/CU = 8 waves/CU. XCD swizzle kept. (r15-verified, 49.0 us)
__global__ __launch_bounds__(512, 2) void flashout_kernel(
    const _Float16* __restrict__ XP, const _Float16* __restrict__ YPc,
    const _Float16* __restrict__ YTc, const int* __restrict__ Lc,
    float* __restrict__ OUT) {
  __shared__ __align__(16) _Float16 yp_t[2][64][264];   // 67584
  __shared__ __align__(16) _Float16 yT_t[2][256][64];   // 65536, chunk^row
  __shared__ __align__(16) _Float16 pbuf[8][16][72];    // 18432

  int t = threadIdx.x;                 // 0..511
  int lane = t & 63, wave = t >> 6;    // wave 0..7
  int g = wave >> 2;                   // tile-half group 0/1
  int wv = wave & 3;                   // wave-in-group
  int tl = t & 255;                    // thread-in-group
  int q = lane >> 4, n15 = lane & 15;
  int wg = (int)blockIdx.x;            // 0..255
  int swz = (wg & 7) * 32 + (wg >> 3); // batch<->XCD, bijective on [0,256)
  int xb = swz & 31;
  int b = swz >> 5;
  int row0 = xb * 64 + wv * 16;

  int lc = Lc[b];
  int T  = (lc + 63) >> 6;             // 64-j tiles
  int tstart = (T * g) >> 1;
  int tend   = (T * (g + 1)) >> 1;
  int nit    = T - (T >> 1);           // ceil(T/2) >= both group counts

  half8 a[8];
  const _Float16* xrow = XP + (size_t)(b * LX_ + row0 + n15) * D_ + q * 8;
  for (int kk = 0; kk < 8; ++kk) a[kk] = *(const half8*)(xrow + kk * 32);

  float m_r[4];
  for (int r = 0; r < 4; ++r) m_r[r] = -1e30f;
  f32x4 lacc = {0.f, 0.f, 0.f, 0.f};
  f32x4 oacc[16];
  for (int dt = 0; dt < 16; ++dt) oacc[dt] = (f32x4){0.f, 0.f, 0.f, 0.f};

  const _Float16* ypb = YPc + (size_t)b * LY_ * D_;
  const _Float16* yTb = YTc + (size_t)b * D_ * LY_;

  uint4v pr[16];
#define PREFETCH(tt)                                                          \
  {                                                                           \
    int y0p = (tt) * 64;                                                      \
    for (int i = 0; i < 8; ++i) {                                             \
      int c = tl + i * 256;                                                   \
      pr[i] = *(const uint4v*)(ypb + (size_t)(y0p + (c >> 5)) * D_ + (c & 31) * 8); \
    }                                                                         \
    for (int i = 0; i < 8; ++i) {                                             \
      int c = tl + i * 256;                                                   \
      pr[8 + i] = *(const uint4v*)(yTb + (size_t)(c >> 3) * LY_ + y0p + (c & 7) * 8); \
    }                                                                         \
  }

  if (tstart < tend) PREFETCH(tstart);

  for (int it = 0; it < nit; ++it) {
    int tt = tstart + it;
    bool val = tt < tend;
    int y0 = tt * 64;
    __syncthreads();   // A: all waves done reading previous tile
    if (val) {
      for (int i = 0; i < 8; ++i) {
        int c = tl + i * 256;
        *(uint4v*)&yp_t[g][c >> 5][(c & 31) * 8] = pr[i];
      }
      for (int i = 0; i < 8; ++i) {
        int c = tl + i * 256;
        int rT = c >> 3, pc = (c & 7) ^ (rT & 7);     // XOR-swizzled chunk
        *(uint4v*)&yT_t[g][rT][pc * 8] = pr[8 + i];
      }
      if (tt + 1 < tend) PREFETCH(tt + 1);
    }
    __syncthreads();   // B: tile staged
    if (!val) continue;   // barriers done; compute section has none

    f32x4 S0 = {0.f, 0.f, 0.f, 0.f}, S1 = {0.f, 0.f, 0.f, 0.f};
    f32x4 S2 = {0.f, 0.f, 0.f, 0.f}, S3 = {0.f, 0.f, 0.f, 0.f};
    for (int kk = 0; kk < 8; ++kk) {
      half8 b0 = *(const half8*)&yp_t[g][n15][kk * 32 + q * 8];
      half8 b1 = *(const half8*)&yp_t[g][16 + n15][kk * 32 + q * 8];
      half8 b2 = *(const half8*)&yp_t[g][32 + n15][kk * 32 + q * 8];
      half8 b3 = *(const half8*)&yp_t[g][48 + n15][kk * 32 + q * 8];
      S0 = __builtin_amdgcn_mfma_f32_16x16x32_f16(a[kk], b0, S0, 0, 0, 0);
      S1 = __builtin_amdgcn_mfma_f32_16x16x32_f16(a[kk], b1, S1, 0, 0, 0);
      S2 = __builtin_amdgcn_mfma_f32_16x16x32_f16(a[kk], b2, S2, 0, 0, 0);
      S3 = __builtin_amdgcn_mfma_f32_16x16x32_f16(a[kk], b3, S3, 0, 0, 0);
    }
    bool mk0 = (y0 + n15) >= lc;
    bool mk1 = (y0 + 16 + n15) >= lc;
    bool mk2 = (y0 + 32 + n15) >= lc;
    bool mk3 = (y0 + 48 + n15) >= lc;

    f32x4 alv;
    bool need = false;
#pragma unroll
    for (int r = 0; r < 4; ++r) {
      float s0 = mk0 ? -1e30f : S0[r];
      float s1 = mk1 ? -1e30f : S1[r];
      float s2 = mk2 ? -1e30f : S2[r];
      float s3 = mk3 ? -1e30f : S3[r];
      float tm = fmaxf(fmaxf(s0, s1), fmaxf(s2, s3));
      tm = fmaxf(tm, __shfl_xor(tm, 1));
      tm = fmaxf(tm, __shfl_xor(tm, 2));
      tm = fmaxf(tm, __shfl_xor(tm, 4));
      tm = fmaxf(tm, __shfl_xor(tm, 8));
      float mn = fmaxf(m_r[r], tm);
      float al = __expf(m_r[r] - mn);
      m_r[r] = mn;
      float p0 = __expf(s0 - mn);
      float p1 = __expf(s1 - mn);
      float p2 = __expf(s2 - mn);
      float p3 = __expf(s3 - mn);
      pbuf[wave][q * 4 + r][n15]      = (_Float16)p0;
      pbuf[wave][q * 4 + r][16 + n15] = (_Float16)p1;
      pbuf[wave][q * 4 + r][32 + n15] = (_Float16)p2;
      pbuf[wave][q * 4 + r][48 + n15] = (_Float16)p3;
      lacc[r] = lacc[r] * al + (p0 + p1) + (p2 + p3);
      alv[r] = al;
      need = need || (al != 1.0f);
    }
    if (__ballot(need)) {
      for (int dt = 0; dt < 16; ++dt)
        for (int r = 0; r < 4; ++r) oacc[dt][r] *= alv[r];
    }
    half8 pa0 = *(const half8*)&pbuf[wave][n15][q * 8];
    half8 pa1 = *(const half8*)&pbuf[wave][n15][32 + q * 8];
    for (int dt = 0; dt < 16; ++dt) {
      int rT = dt * 16 + n15, x = rT & 7;
      half8 bb0 = *(const half8*)&yT_t[g][rT][(q ^ x) * 8];
      half8 bb1 = *(const half8*)&yT_t[g][rT][((4 + q) ^ x) * 8];
      oacc[dt] = __builtin_amdgcn_mfma_f32_16x16x32_f16(pa0, bb0, oacc[dt], 0, 0, 0);
      oacc[dt] = __builtin_amdgcn_mfma_f32_16x16x32_f16(pa1, bb1, oacc[dt], 0, 0, 0);
    }
  }
#undef PREFETCH

  // reduce per-lane partial l across the 16-lane column group
  for (int r = 0; r < 4; ++r) {
    float v = lacc[r];
    v += __shfl_xor(v, 1);
    v += __shfl_xor(v, 2);
    v += __shfl_xor(v, 4);
    v += __shfl_xor(v, 8);
    lacc[r] = v;
  }

  // ---- in-block merge of the two tile-halves --------------------------
  __syncthreads();   // all staging reads done; LDS reusable
  _Float16 (*Obuf)[256] = (_Float16(*)[256])&yp_t[0][0][0];  // 32768 B
  float (*ml)[2] = (float(*)[2])&yT_t[0][0][0];              //   512 B
  if (g == 1) {
    for (int dt = 0; dt < 16; ++dt)
      for (int r = 0; r < 4; ++r)
        Obuf[wv * 16 + q * 4 + r][dt * 16 + n15] = (_Float16)oacc[dt][r];
    if (n15 == 0)
      for (int r = 0; r < 4; ++r) {
        ml[wv * 16 + q * 4 + r][0] = m_r[r];
        ml[wv * 16 + q * 4 + r][1] = lacc[r];
      }
  }
  __syncthreads();
  if (g == 0) {
    for (int r = 0; r < 4; ++r) {
      int rl = wv * 16 + q * 4 + r;
      float m1 = ml[rl][0], l1 = ml[rl][1];
      float m0 = m_r[r], l0 = lacc[r];
      float mm = fmaxf(m0, m1);
      float w0 = __expf(m0 - mm), w1 = __expf(m1 - mm);
      float inv = 1.0f / (l0 * w0 + l1 * w1);
      float* orow = OUT + (size_t)(b * LX_ + xb * 64 + rl) * D_;
      for (int dt = 0; dt < 16; ++dt) {
        float o1 = (float)Obuf[rl][dt * 16 + n15];
        orow[dt * 16 + n15] = (oacc[dt][r] * w0 + o1 * w1) * inv;
      }
    }
  }
}

extern "C" void kernel_launch(void* const* d_in, const int* in_sizes, int n_in,
                              void* d_out, int out_size, void* d_ws, size_t ws_size,
                              hipStream_t stream) {
  const float* x     = (const float*)d_in[0];  // [8,2048,256]
  const float* y     = (const float*)d_in[1];  // [8,2048,256]
  const int*   ymask = (const int*)  d_in[2];  // [8,2048]
  const float* W     = (const float*)d_in[3];  // [256,256]
  const float* bias  = (const float*)d_in[4];  // [256]
  float* out = (float*)d_out;

  // ws layout (~25 MB): PO/Pm/Pl no longer needed
  char* ws = (char*)d_ws;
  size_t o = 0;
  unsigned short* Whi = (unsigned short*)(ws + o); o += 131072;
  unsigned short* Wlo = (unsigned short*)(ws + o); o += 131072;
  _Float16* XP  = (_Float16*)(ws + o); o += 8388608;
  _Float16* YPc = (_Float16*)(ws + o); o += 8388608;
  _Float16* YTc = (_Float16*)(ws + o); o += 8388608;
  int*   CIDX = (int*)  (ws + o); o += 65536;
  int*   Lc   = (int*)  (ws + o);

  prep_kernel<<<40, 256, 0, stream>>>(W, Whi, Wlo, ymask, CIDX, Lc);
  projgather_kernel<<<1536, 256, 0, stream>>>(x, y, bias, Whi, Wlo, CIDX, Lc,
                                              XP, YPc, YTc);
  flashout_kernel<<<256, 512, 0, stream>>>(XP, YPc, YTc, Lc, out);
}